// Round 11
// baseline (327.280 us; speedup 1.0000x reference)
//
#include <hip/hip_runtime.h>
#include <hip/hip_cooperative_groups.h>
#include <hip/hip_fp16.h>
#include <math.h>

#define N_NODES 50000
#define N_EDGES 800000
#define D_FEAT 128

#define BSHIFT 6
#define BNODES 64                                  // nodes per bucket (pow2)
#define NBUCK ((N_NODES + BNODES - 1) / BNODES)    // 782
#define BCAP 1280                                  // edges/bucket cap (mean 1024 + 8 sigma)
#define SLOT_CAP 64                                // max degree per node (mean 16)

#define BLOCK 512
#define MAXGRID 512
#define PREP_GRID 512

typedef __attribute__((ext_vector_type(4))) _Float16 half4;
namespace cg = cooperative_groups;

// One explicit LDS union reused by all phases (33 KB).
struct SmemLayout {
    int   cnt[BNODES];              // slot counters / reduce scratch
    float scal[4];                  // Mlg, ppl, ke
    int   slot[BNODES][SLOT_CAP];   // 16 KB; phase B: h_row
    float dsv[BNODES][SLOT_CAP];    // 16 KB; phase B: h_col
};

// ---------- Phase A: zero cursors; fp16 convert + per-block max partial ----------
__device__ __forceinline__ void phase_cvtmax(const float* __restrict__ x,
                                             half4* __restrict__ x16,
                                             float* __restrict__ partials,
                                             int* __restrict__ gcur,
                                             SmemLayout& sm) {
    const int tid = threadIdx.x;
    const int gtid = blockIdx.x * BLOCK + tid;
    if (gtid < 2 * NBUCK) gcur[gtid] = 0;
    const float4* x4 = (const float4*)x;
    const int total4 = N_NODES * D_FEAT / 4;
    const int stride = gridDim.x * BLOCK;
    float m = -INFINITY;
    for (int i = gtid; i < total4; i += stride) {
        float4 v = x4[i];
        m = fmaxf(m, fmaxf(fmaxf(v.x, v.y), fmaxf(v.z, v.w)));
        half4 h;
        h.x = (_Float16)v.x; h.y = (_Float16)v.y;
        h.z = (_Float16)v.z; h.w = (_Float16)v.w;
        x16[i] = h;
    }
    for (int off = 32; off > 0; off >>= 1)
        m = fmaxf(m, __shfl_down(m, off, 64));
    float* red = (float*)sm.cnt;
    const int lane = tid & 63, wid = tid >> 6;
    if (lane == 0) red[wid] = m;
    __syncthreads();
    if (tid == 0) {
        for (int w = 1; w < BLOCK / 64; ++w) m = fmaxf(m, red[w]);
        partials[blockIdx.x] = m;
    }
    __syncthreads();
}

// ---------- Phase B: radix partition by row-bucket and col-bucket ----------
__device__ __forceinline__ void phase_part(const int* __restrict__ row,
                                           const int* __restrict__ col,
                                           int* __restrict__ gcur,
                                           int2* __restrict__ be_row,
                                           int* __restrict__ be_col,
                                           SmemLayout& sm) {
    int* h_row = (int*)sm.slot;
    int* h_col = (int*)sm.dsv;
    const int tid = threadIdx.x;
    const int G = gridDim.x;
    const int echunk = (N_EDGES + G - 1) / G;
    const int e0 = blockIdx.x * echunk;
    const int e1 = min(e0 + echunk, N_EDGES);
    for (int i = tid; i < NBUCK; i += BLOCK) { h_row[i] = 0; h_col[i] = 0; }
    __syncthreads();
    for (int e = e0 + tid; e < e1; e += BLOCK) {
        atomicAdd(&h_row[row[e] >> BSHIFT], 1);
        atomicAdd(&h_col[col[e] >> BSHIFT], 1);
    }
    __syncthreads();
    for (int i = tid; i < NBUCK; i += BLOCK) {
        h_row[i] = i * BCAP + atomicAdd(&gcur[i], h_row[i]);
        h_col[i] = i * BCAP + atomicAdd(&gcur[NBUCK + i], h_col[i]);
    }
    __syncthreads();
    for (int e = e0 + tid; e < e1; e += BLOCK) {
        int r = row[e], c = col[e];
        int pr = atomicAdd(&h_row[r >> BSHIFT], 1);
        if (pr < (r >> BSHIFT) * BCAP + BCAP) be_row[pr] = make_int2(r, c);
        int pc = atomicAdd(&h_col[c >> BSHIFT], 1);
        if (pc < (c >> BSHIFT) * BCAP + BCAP) be_col[pc] = c;
    }
}

// ---------- Phase C: per-bucket in-degree -> dis = rsqrt(deg_col) ----------
__device__ __forceinline__ void phase_degcol(const int* __restrict__ gcur,
                                             const int* __restrict__ be_col,
                                             float* __restrict__ dis,
                                             SmemLayout& sm) {
    const int tid = threadIdx.x;
    for (int b = blockIdx.x; b < NBUCK; b += gridDim.x) {
        if (tid < BNODES) sm.cnt[tid] = 0;
        __syncthreads();
        int cnt = min(gcur[NBUCK + b], BCAP);
        int base = b * BCAP;
        for (int k = tid; k < cnt; k += BLOCK)
            atomicAdd(&sm.cnt[be_col[base + k] & (BNODES - 1)], 1);
        __syncthreads();
        if (tid < BNODES) {
            int n = (b << BSHIFT) + tid;
            if (n < N_NODES) {
                int d0 = sm.cnt[tid];
                dis[n] = (d0 > 0) ? rsqrtf((float)d0) : 0.0f;
            }
        }
        __syncthreads();
    }
}

// ---------- scalars: reduce partials -> Mlg, ppl, ke in LDS ----------
__device__ __forceinline__ void phase_scal(const float* __restrict__ partials,
                                           int nparts,
                                           const float* __restrict__ eps_p,
                                           const float* __restrict__ p_p,
                                           SmemLayout& sm) {
    const int tid = threadIdx.x;
    float m = (tid < nparts) ? partials[tid] : -INFINITY;
    for (int off = 32; off > 0; off >>= 1)
        m = fmaxf(m, __shfl_down(m, off, 64));
    float* red = (float*)sm.cnt;
    const int lane = tid & 63, wid = tid >> 6;
    if (lane == 0) red[wid] = m;
    __syncthreads();
    if (tid == 0) {
        for (int w = 1; w < BLOCK / 64; ++w) m = fmaxf(m, red[w]);
        float pp = 2.0f / (1.0f + __expf(-p_p[0]));
        const float LOG2E = 1.44269504f;
        sm.scal[0] = pp * m * LOG2E;   // Mlg
        sm.scal[1] = pp * LOG2E;       // ppl
        sm.scal[2] = 1.0f + eps_p[0];  // ke
    }
    __syncthreads();
}

// ---------- Phase D: slot-build (LDS) + aggregation ----------
__device__ __forceinline__ void phase_agg(const float* __restrict__ x,
                                          const half4* __restrict__ x16,
                                          const int* __restrict__ gcur,
                                          const int2* __restrict__ be_row,
                                          const float* __restrict__ dis,
                                          float* __restrict__ out,
                                          SmemLayout& sm) {
    const int tid = threadIdx.x;
    const float Mlg = sm.scal[0], ppl = sm.scal[1], ke = sm.scal[2];
    const float4* x4 = (const float4*)x;
    for (int b = blockIdx.x; b < NBUCK; b += gridDim.x) {
        if (tid < BNODES) sm.cnt[tid] = 0;
        __syncthreads();
        int ecnt = min(gcur[b], BCAP);
        int base = b * BCAP;
        for (int k = tid; k < ecnt; k += BLOCK) {
            int2 e = be_row[base + k];
            int ln = e.x & (BNODES - 1);
            int pos = atomicAdd(&sm.cnt[ln], 1);
            if (pos < SLOT_CAP) {
                sm.slot[ln][pos] = e.y;
                sm.dsv[ln][pos] = dis[e.y];
            }
        }
        __syncthreads();
        int g = tid >> 5;   // node group 0..15
        int t = tid & 31;   // float4 feat group
        for (int ln = g; ln < BNODES; ln += 16) {
            int n = (b << BSHIFT) + ln;
            if (n >= N_NODES) continue;
            int cnt = min(sm.cnt[ln], SLOT_CAP);
            float dn = dis[n];
            float4 S = make_float4(0.f, 0.f, 0.f, 0.f);
            float4 T = make_float4(0.f, 0.f, 0.f, 0.f);
            #pragma unroll 4
            for (int j = 0; j < cnt; ++j) {
                int c = sm.slot[ln][j];
                float nr = dn * sm.dsv[ln][j];
                half4 hv = x16[c * 32 + t];
                float x0 = (float)hv.x, x1 = (float)hv.y;
                float x2 = (float)hv.z, x3 = (float)hv.w;
                float e0 = exp2f(fmaf(ppl, x0, -Mlg));
                float e1 = exp2f(fmaf(ppl, x1, -Mlg));
                float e2 = exp2f(fmaf(ppl, x2, -Mlg));
                float e3 = exp2f(fmaf(ppl, x3, -Mlg));
                float w0 = nr * e0, w1 = nr * e1, w2 = nr * e2, w3 = nr * e3;
                S.x += w0; S.y += w1; S.z += w2; S.w += w3;
                T.x = fmaf(w0, x0, T.x);
                T.y = fmaf(w1, x1, T.y);
                T.z = fmaf(w2, x2, T.z);
                T.w = fmaf(w3, x3, T.w);
            }
            float4 xn = x4[n * 32 + t];
            float4 o;
            o.x = T.x / (S.x + 1e-6f) + ke * xn.x;
            o.y = T.y / (S.y + 1e-6f) + ke * xn.y;
            o.z = T.z / (S.z + 1e-6f) + ke * xn.z;
            o.w = T.w / (S.w + 1e-6f) + ke * xn.w;
            ((float4*)out)[n * 32 + t] = o;
        }
        __syncthreads();
    }
}

// ---------------- cooperative single-dispatch kernel ----------------
__global__ void __launch_bounds__(BLOCK, 4) k_fused(
    const float* __restrict__ x,
    const int* __restrict__ row,
    const int* __restrict__ col,
    const float* __restrict__ eps_p,
    const float* __restrict__ p_p,
    float* __restrict__ out,
    half4* __restrict__ x16,
    float* __restrict__ partials,
    int* __restrict__ gcur,
    int2* __restrict__ be_row,
    int* __restrict__ be_col,
    float* __restrict__ dis)
{
    cg::grid_group grid = cg::this_grid();
    __shared__ SmemLayout sm;
    phase_cvtmax(x, x16, partials, gcur, sm);
    grid.sync();
    phase_part(row, col, gcur, be_row, be_col, sm);
    grid.sync();
    phase_degcol(gcur, be_col, dis, sm);
    grid.sync();
    phase_scal(partials, gridDim.x, eps_p, p_p, sm);
    phase_agg(x, x16, gcur, be_row, dis, out, sm);
}

// ---------------- fallback 3-dispatch pipeline ----------------
__global__ void __launch_bounds__(BLOCK) k_prep(
    const float* __restrict__ x, const int* __restrict__ row,
    const int* __restrict__ col, half4* __restrict__ x16,
    float* __restrict__ partials, int* __restrict__ gcur,
    int2* __restrict__ be_row, int* __restrict__ be_col)
{
    __shared__ SmemLayout sm;
    phase_cvtmax(x, x16, partials, gcur, sm);
    __syncthreads();
    phase_part(row, col, gcur, be_row, be_col, sm);
}

__global__ void __launch_bounds__(BLOCK) k_deg(
    const int* __restrict__ gcur, const int* __restrict__ be_col,
    float* __restrict__ dis)
{
    __shared__ SmemLayout sm;
    phase_degcol(gcur, be_col, dis, sm);
}

__global__ void __launch_bounds__(BLOCK) k_aggk(
    const float* __restrict__ x, const half4* __restrict__ x16,
    const float* __restrict__ partials, int nparts,
    const float* __restrict__ eps_p, const float* __restrict__ p_p,
    const int* __restrict__ gcur, const int2* __restrict__ be_row,
    const float* __restrict__ dis, float* __restrict__ out)
{
    __shared__ SmemLayout sm;
    phase_scal(partials, nparts, eps_p, p_p, sm);
    phase_agg(x, x16, gcur, be_row, dis, out, sm);
}

extern "C" void kernel_launch(void* const* d_in, const int* in_sizes, int n_in,
                              void* d_out, int out_size, void* d_ws, size_t ws_size,
                              hipStream_t stream) {
    const float* x   = (const float*)d_in[0];
    const int*   ei  = (const int*)d_in[1];   // [2, E]: row = ei[0:E], col = ei[E:2E]
    const float* eps = (const float*)d_in[2];
    const float* p   = (const float*)d_in[3];
    float* out = (float*)d_out;

    const int* row = ei;
    const int* col = ei + N_EDGES;

    // Workspace: gcur[2*NBUCK] | partials[MAXGRID] | dis[N] | pad | x16 | be_col | be_row
    char* ws = (char*)d_ws;
    int*   gcur     = (int*)ws;
    float* partials = (float*)(ws + 4 * 2 * NBUCK);
    float* dis      = (float*)(ws + 4 * (2 * NBUCK + MAXGRID));
    size_t off = 4 * (size_t)(2 * NBUCK + MAXGRID + N_NODES);
    off = (off + 15) & ~(size_t)15;
    half4* x16      = (half4*)(ws + off);
    off += (size_t)N_NODES * D_FEAT * 2;               // 12.8 MB
    int*   be_col   = (int*)(ws + off);
    off += (size_t)NBUCK * BCAP * 4;                   // 4.0 MB
    int2*  be_row   = (int2*)(ws + off);               // 8.0 MB

    // Try the single cooperative dispatch; fall back to 3 dispatches on failure.
    int maxB = 0;
    hipError_t oe = hipOccupancyMaxActiveBlocksPerMultiprocessor(&maxB, k_fused, BLOCK, 0);
    bool coop_done = false;
    if (oe == hipSuccess && maxB > 0) {
        int g = maxB * 256;
        if (g > MAXGRID) g = MAXGRID;
        void* args[] = { (void*)&x, (void*)&row, (void*)&col, (void*)&eps, (void*)&p,
                         (void*)&out, (void*)&x16, (void*)&partials, (void*)&gcur,
                         (void*)&be_row, (void*)&be_col, (void*)&dis };
        hipError_t le = hipLaunchCooperativeKernel((const void*)k_fused, dim3(g),
                                                   dim3(BLOCK), args, 0, stream);
        coop_done = (le == hipSuccess);
    }
    if (!coop_done) {
        k_prep<<<PREP_GRID, BLOCK, 0, stream>>>(x, row, col, x16, partials, gcur,
                                                be_row, be_col);
        k_deg<<<NBUCK, BLOCK, 0, stream>>>(gcur, be_col, dis);
        k_aggk<<<NBUCK, BLOCK, 0, stream>>>(x, x16, partials, PREP_GRID, eps, p,
                                            gcur, be_row, dis, out);
    }
}

// Round 12
// 177.644 us; speedup vs baseline: 1.8423x; 1.8423x over previous
//
#include <hip/hip_runtime.h>
#include <hip/hip_fp16.h>
#include <math.h>

#define N_NODES 50000
#define N_EDGES 800000
#define D_FEAT 128

#define BSHIFT 5
#define BNODES 32                                  // nodes per bucket (pow2)
#define NBUCK ((N_NODES + BNODES - 1) / BNODES)    // 1563
#define BCAP 704                                   // edges/bucket cap (mean 512 + 8.5 sigma)
#define SLOT_CAP 64                                // max degree per node (mean 16)

#define PREP_GRID 256
#define PREP_BLOCK 512
#define PREP_CHUNK (N_EDGES / PREP_GRID)           // 3125 exact
#define AGG_BLOCK 256

typedef __attribute__((ext_vector_type(4))) _Float16 half4;

// ---------------- k_prep: fp16 convert + max partials, then radix partition ----------------
// Phases are cross-block independent; only __syncthreads inside. gcur zeroed by memset.
__global__ void __launch_bounds__(PREP_BLOCK) k_prep(
    const float* __restrict__ x, const int* __restrict__ row,
    const int* __restrict__ col, half4* __restrict__ x16,
    float* __restrict__ partials, int* __restrict__ gcur,
    int2* __restrict__ be_row, int* __restrict__ be_col)
{
    __shared__ int h_row[NBUCK];    // 6.25 KB
    __shared__ int h_col[NBUCK];    // 6.25 KB
    __shared__ float red[PREP_BLOCK / 64];
    const int tid = threadIdx.x;

    // phase A: convert x -> fp16, per-block max partial
    {
        const float4* x4 = (const float4*)x;
        const int total4 = N_NODES * D_FEAT / 4;
        float m = -INFINITY;
        for (int i = blockIdx.x * PREP_BLOCK + tid; i < total4; i += PREP_GRID * PREP_BLOCK) {
            float4 v = x4[i];
            m = fmaxf(m, fmaxf(fmaxf(v.x, v.y), fmaxf(v.z, v.w)));
            half4 h;
            h.x = (_Float16)v.x; h.y = (_Float16)v.y;
            h.z = (_Float16)v.z; h.w = (_Float16)v.w;
            x16[i] = h;
        }
        for (int off = 32; off > 0; off >>= 1)
            m = fmaxf(m, __shfl_down(m, off, 64));
        if ((tid & 63) == 0) red[tid >> 6] = m;
        __syncthreads();
        if (tid == 0) {
            for (int w = 1; w < PREP_BLOCK / 64; ++w) m = fmaxf(m, red[w]);
            partials[blockIdx.x] = m;
        }
    }

    // phase B: radix partition by row-bucket and col-bucket
    for (int i = tid; i < NBUCK; i += PREP_BLOCK) { h_row[i] = 0; h_col[i] = 0; }
    __syncthreads();
    const int e0 = blockIdx.x * PREP_CHUNK;
    const int e1 = e0 + PREP_CHUNK;
    for (int e = e0 + tid; e < e1; e += PREP_BLOCK) {
        atomicAdd(&h_row[row[e] >> BSHIFT], 1);
        atomicAdd(&h_col[col[e] >> BSHIFT], 1);
    }
    __syncthreads();
    for (int i = tid; i < NBUCK; i += PREP_BLOCK) {
        h_row[i] = i * BCAP + atomicAdd(&gcur[i], h_row[i]);
        h_col[i] = i * BCAP + atomicAdd(&gcur[NBUCK + i], h_col[i]);
    }
    __syncthreads();
    for (int e = e0 + tid; e < e1; e += PREP_BLOCK) {
        int r = row[e], c = col[e];
        int pr = atomicAdd(&h_row[r >> BSHIFT], 1);
        if (pr < (r >> BSHIFT) * BCAP + BCAP) be_row[pr] = make_int2(r, c);
        int pc = atomicAdd(&h_col[c >> BSHIFT], 1);
        if (pc < (c >> BSHIFT) * BCAP + BCAP) be_col[pc] = c;
    }
}

// ---------------- k_deg: per-bucket in-degree -> dis = rsqrt(deg_col) ----------------
__global__ void __launch_bounds__(AGG_BLOCK) k_deg(
    const int* __restrict__ gcur, const int* __restrict__ be_col,
    float* __restrict__ dis)
{
    __shared__ int hcnt[BNODES];
    const int b = blockIdx.x;
    if (threadIdx.x < BNODES) hcnt[threadIdx.x] = 0;
    __syncthreads();
    int cnt = min(gcur[NBUCK + b], BCAP);
    int base = b * BCAP;
    for (int k = threadIdx.x; k < cnt; k += AGG_BLOCK)
        atomicAdd(&hcnt[be_col[base + k] & (BNODES - 1)], 1);
    __syncthreads();
    if (threadIdx.x < BNODES) {
        int n = (b << BSHIFT) + threadIdx.x;
        if (n < N_NODES) {
            int d = hcnt[threadIdx.x];
            dis[n] = (d > 0) ? rsqrtf((float)d) : 0.0f;
        }
    }
}

// ---------------- k_agg: scalars + slot-build (LDS) + aggregation ----------------
// One 256-thread block per 32-node bucket; 16.5 KB LDS -> 8 blocks/CU (100% waves).
__global__ void __launch_bounds__(AGG_BLOCK, 8) k_agg(
    const float* __restrict__ x, const half4* __restrict__ x16,
    const float* __restrict__ partials,
    const float* __restrict__ eps_p, const float* __restrict__ p_p,
    const int* __restrict__ gcur, const int2* __restrict__ be_row,
    const float* __restrict__ dis, float* __restrict__ out)
{
    __shared__ int s_cnt[BNODES];
    __shared__ int s_slot[BNODES][SLOT_CAP];     // 8 KB
    __shared__ float s_dis[BNODES][SLOT_CAP];    // 8 KB
    __shared__ float s_scal[4];
    __shared__ float red[AGG_BLOCK / 64];
    const int tid = threadIdx.x;

    // scalars: reduce 256 partials (redundant per block; L2-hit)
    {
        float m = partials[tid];   // PREP_GRID == AGG_BLOCK == 256
        for (int off = 32; off > 0; off >>= 1)
            m = fmaxf(m, __shfl_down(m, off, 64));
        if ((tid & 63) == 0) red[tid >> 6] = m;
        if (tid < BNODES) s_cnt[tid] = 0;
        __syncthreads();
        if (tid == 0) {
            for (int w = 1; w < AGG_BLOCK / 64; ++w) m = fmaxf(m, red[w]);
            float pp = 2.0f / (1.0f + __expf(-p_p[0]));
            const float LOG2E = 1.44269504f;
            s_scal[0] = pp * m * LOG2E;   // Mlg
            s_scal[1] = pp * LOG2E;       // ppl
            s_scal[2] = 1.0f + eps_p[0];  // ke
        }
        __syncthreads();
    }
    const float Mlg = s_scal[0], ppl = s_scal[1], ke = s_scal[2];

    // slot build in LDS
    const int b = blockIdx.x;
    int ecnt = min(gcur[b], BCAP);
    int base = b * BCAP;
    for (int k = tid; k < ecnt; k += AGG_BLOCK) {
        int2 e = be_row[base + k];
        int ln = e.x & (BNODES - 1);
        int pos = atomicAdd(&s_cnt[ln], 1);
        if (pos < SLOT_CAP) {
            s_slot[ln][pos] = e.y;
            s_dis[ln][pos] = dis[e.y];
        }
    }
    __syncthreads();

    // aggregate: 8 node-groups x 32 threads; thread owns 4 feats (half4/float4)
    const int g = tid >> 5, t = tid & 31;
    const float4* x4 = (const float4*)x;
    for (int ln = g; ln < BNODES; ln += AGG_BLOCK / 32) {
        int n = (b << BSHIFT) + ln;
        if (n >= N_NODES) continue;
        int cnt = min(s_cnt[ln], SLOT_CAP);
        float dn = dis[n];
        float4 S = make_float4(0.f, 0.f, 0.f, 0.f);
        float4 T = make_float4(0.f, 0.f, 0.f, 0.f);
        #pragma unroll 4
        for (int j = 0; j < cnt; ++j) {
            int c = s_slot[ln][j];
            float nr = dn * s_dis[ln][j];
            half4 hv = x16[c * 32 + t];
            float x0 = (float)hv.x, x1 = (float)hv.y;
            float x2 = (float)hv.z, x3 = (float)hv.w;
            float e0 = exp2f(fmaf(ppl, x0, -Mlg));
            float e1 = exp2f(fmaf(ppl, x1, -Mlg));
            float e2 = exp2f(fmaf(ppl, x2, -Mlg));
            float e3 = exp2f(fmaf(ppl, x3, -Mlg));
            float w0 = nr * e0, w1 = nr * e1, w2 = nr * e2, w3 = nr * e3;
            S.x += w0; S.y += w1; S.z += w2; S.w += w3;
            T.x = fmaf(w0, x0, T.x);
            T.y = fmaf(w1, x1, T.y);
            T.z = fmaf(w2, x2, T.z);
            T.w = fmaf(w3, x3, T.w);
        }
        float4 xn = x4[n * 32 + t];
        float4 o;
        o.x = T.x / (S.x + 1e-6f) + ke * xn.x;
        o.y = T.y / (S.y + 1e-6f) + ke * xn.y;
        o.z = T.z / (S.z + 1e-6f) + ke * xn.z;
        o.w = T.w / (S.w + 1e-6f) + ke * xn.w;
        ((float4*)out)[n * 32 + t] = o;
    }
}

extern "C" void kernel_launch(void* const* d_in, const int* in_sizes, int n_in,
                              void* d_out, int out_size, void* d_ws, size_t ws_size,
                              hipStream_t stream) {
    const float* x   = (const float*)d_in[0];
    const int*   ei  = (const int*)d_in[1];   // [2, E]: row = ei[0:E], col = ei[E:2E]
    const float* eps = (const float*)d_in[2];
    const float* p   = (const float*)d_in[3];
    float* out = (float*)d_out;

    const int* row = ei;
    const int* col = ei + N_EDGES;

    // Workspace: gcur[2*NBUCK] | partials[256] | dis[N] | pad16 | x16 (12.8MB)
    //            | be_col[NBUCK*BCAP] (4.4MB) | be_row[NBUCK*BCAP] int2 (8.8MB)
    char* ws = (char*)d_ws;
    int*   gcur     = (int*)ws;
    float* partials = (float*)(ws + 4 * 2 * NBUCK);
    float* dis      = (float*)(ws + 4 * (2 * NBUCK + 256));
    size_t off = 4 * (size_t)(2 * NBUCK + 256 + N_NODES);
    off = (off + 15) & ~(size_t)15;
    half4* x16      = (half4*)(ws + off);
    off += (size_t)N_NODES * D_FEAT * 2;               // 12.8 MB
    int*   be_col   = (int*)(ws + off);
    off += (size_t)NBUCK * BCAP * 4;                   // 4.4 MB
    off = (off + 7) & ~(size_t)7;
    int2*  be_row   = (int2*)(ws + off);               // 8.8 MB
    // total ~ 26.3 MB

    hipMemsetAsync(gcur, 0, 4 * 2 * NBUCK, stream);
    k_prep<<<PREP_GRID, PREP_BLOCK, 0, stream>>>(x, row, col, x16, partials, gcur,
                                                 be_row, be_col);
    k_deg<<<NBUCK, AGG_BLOCK, 0, stream>>>(gcur, be_col, dis);
    k_agg<<<NBUCK, AGG_BLOCK, 0, stream>>>(x, x16, partials, eps, p,
                                           gcur, be_row, dis, out);
}